// Round 2
// baseline (247.664 us; speedup 1.0000x reference)
//
#include <hip/hip_runtime.h>

#define HD 128
#define LSEQ 200
#define BATCH 2048
#define NE 8
#define SWH 64

#define BM 64        // tokens per block-tile
#define LDX 136      // padded bf16 row stride for x tile
#define LDH 264      // padded bf16 row stride for hidden tile
#define NTILES ((BATCH * LSEQ) / BM)   // 6400
#define GRID 768     // 3 blocks/CU * 256 CU, all co-resident

typedef float f32x4 __attribute__((ext_vector_type(4)));
typedef __bf16 bf16x8 __attribute__((ext_vector_type(8)));

static __device__ __forceinline__ unsigned short f2bf(float f) {
    union { float f; unsigned u; } v; v.f = f;
    unsigned u = v.u;
    u += 0x7fffu + ((u >> 16) & 1u);   // round-to-nearest-even
    return (unsigned short)(u >> 16);
}

// ---------------- fused routing + weight prep ----------------
// Every block redundantly computes the route (deterministic), then converts
// its slice of the concatenated weights to bf16 in workspace.
// W1c [256][128]: rows 0-127 = uW1, rows 128-255 = eW1[route]
// W2c [128][256]: cols 0-127 = uW2, cols 128-255 = eW2[route]
__global__ void prep_route(const float* __restrict__ x_real,
                           const float* __restrict__ sW1, const float* __restrict__ sb1,
                           const float* __restrict__ sW2, const float* __restrict__ sb2,
                           const float* __restrict__ uW1, const float* __restrict__ ub1,
                           const float* __restrict__ uW2, const float* __restrict__ ub2,
                           const float* __restrict__ eW1, const float* __restrict__ eb1,
                           const float* __restrict__ eW2, const float* __restrict__ eb2,
                           float* __restrict__ out_tail,
                           unsigned short* __restrict__ W1c, unsigned short* __restrict__ W2c,
                           float* __restrict__ b1c, float* __restrict__ b2s) {
    __shared__ float part[256];
    __shared__ float xm[HD];
    __shared__ float hsw[SWH];
    __shared__ float logits[NE];
    __shared__ int route_s;
    const int t = threadIdx.x;   // 256 threads

    { // mean over sequence, split into two half-sums per column
        int col = t & 127, half = t >> 7;
        float s = 0.f;
        for (int l = half * 100; l < half * 100 + 100; ++l) s += x_real[l * HD + col];
        part[t] = s;
    }
    __syncthreads();
    if (t < HD) xm[t] = (part[t] + part[t + 128]) * (1.0f / LSEQ);
    __syncthreads();
    if (t < SWH) {
        float s = sb1[t];
        for (int k = 0; k < HD; ++k) s += xm[k] * sW1[t * HD + k];
        hsw[t] = s > 0.f ? s : 0.f;
    }
    __syncthreads();
    if (t < NE) {
        float s = sb2[t];
        for (int k = 0; k < SWH; ++k) s += hsw[k] * sW2[t * SWH + k];
        logits[t] = s;
    }
    __syncthreads();
    if (t == 0) {
        float mx = logits[0]; int am = 0;
        for (int e = 1; e < NE; ++e) if (logits[e] > mx) { mx = logits[e]; am = e; }
        float den = 0.f;
        for (int e = 0; e < NE; ++e) den += __expf(logits[e] - mx);
        route_s = am;
        if (blockIdx.x == 0) {
            out_tail[0] = (float)am;      // route
            out_tail[1] = 1.0f / den;     // out_prob_max = exp(0)/den
        }
    }
    __syncthreads();
    const int r = route_s;

    const int i = blockIdx.x * 256 + t;   // 0 .. 32767
    if (i < 2 * HD * HD) {
        int o = i >> 7, k = i & 127;
        float v1 = (o < HD) ? uW1[o * HD + k] : eW1[r * HD * HD + (o - HD) * HD + k];
        W1c[i] = f2bf(v1);
        int o2 = i >> 8, j = i & 255;
        float v2 = (j < HD) ? uW2[o2 * HD + j] : eW2[r * HD * HD + o2 * HD + (j - HD)];
        W2c[i] = f2bf(v2);
    }
    if (i < 2 * HD) b1c[i] = (i < HD) ? ub1[i] : eb1[r * HD + (i - HD)];
    if (i < HD)     b2s[i] = ub2[i] + eb2[r * HD + i];
}

// ---------------- main: persistent blocks, fused 2-stage GEMM, reg-prefetch ----------------
__global__ __launch_bounds__(256, 3)
void moe_main(const float* __restrict__ x,
              const unsigned short* __restrict__ W1c, const unsigned short* __restrict__ W2c,
              const float* __restrict__ b1c, const float* __restrict__ b2s,
              float* __restrict__ out) {
    __shared__ __align__(16) unsigned short xs[BM * LDX];  // 17408 B
    __shared__ __align__(16) unsigned short hs[BM * LDH];  // 33792 B

    const int t = threadIdx.x;
    const int lane = t & 63;
    const int w = t >> 6;          // wave 0..3
    const int l16 = lane & 15;
    const int lq = lane >> 4;      // quadrant 0..3
    const int ncb = w * 64;        // GEMM1: this wave's 64 hidden columns
    const int ncb2 = w * 32;       // GEMM2: this wave's 32 output columns

    // hoist biases (loop-invariant)
    float bias1[4], bias2[2];
#pragma unroll
    for (int nt = 0; nt < 4; ++nt) bias1[nt] = b1c[ncb + nt * 16 + l16];
#pragma unroll
    for (int nt = 0; nt < 2; ++nt) bias2[nt] = b2s[ncb2 + nt * 16 + l16];

    int tile = blockIdx.x;
    float4 pv[8];
    { // prefetch first tile
        const float4* x4 = (const float4*)(x + (size_t)tile * (BM * HD));
#pragma unroll
        for (int i = 0; i < 8; ++i) pv[i] = x4[t + i * 256];
    }

    while (tile < NTILES) {
        const int ntile = tile + GRID;

        // ---- stage prefetched x tile (f32 -> bf16) into LDS ----
#pragma unroll
        for (int i = 0; i < 8; ++i) {
            int idx = t + i * 256;       // 0..2047 float4 units
            int row = idx >> 5;          // 32 float4 per row
            int c4 = idx & 31;
            ushort4 b;
            b.x = f2bf(pv[i].x); b.y = f2bf(pv[i].y);
            b.z = f2bf(pv[i].z); b.w = f2bf(pv[i].w);
            *(ushort4*)&xs[row * LDX + c4 * 4] = b;
        }
        __syncthreads();

        // ---- issue next tile's global loads (consumed next iteration) ----
        if (ntile < NTILES) {
            const float4* x4 = (const float4*)(x + (size_t)ntile * (BM * HD));
#pragma unroll
            for (int i = 0; i < 8; ++i) pv[i] = x4[t + i * 256];
        }

        // ---- GEMM1: Hmid[64][256] = relu(X[64][128] @ W1c^T + b1c) ----
        f32x4 acc1[4][4] = {};
        for (int ks = 0; ks < 4; ++ks) {
            const int kofs = ks * 32 + lq * 8;
            bf16x8 a[4], b[4];
#pragma unroll
            for (int mt = 0; mt < 4; ++mt)
                a[mt] = *(const bf16x8*)&xs[(mt * 16 + l16) * LDX + kofs];
#pragma unroll
            for (int nt = 0; nt < 4; ++nt)
                b[nt] = *(const bf16x8*)&W1c[(ncb + nt * 16 + l16) * HD + kofs];
#pragma unroll
            for (int mt = 0; mt < 4; ++mt)
#pragma unroll
                for (int nt = 0; nt < 4; ++nt)
                    acc1[mt][nt] = __builtin_amdgcn_mfma_f32_16x16x32_bf16(
                        a[mt], b[nt], acc1[mt][nt], 0, 0, 0);
        }
        // bias + relu + store hidden to LDS (bf16)
#pragma unroll
        for (int nt = 0; nt < 4; ++nt) {
            const int col = ncb + nt * 16 + l16;
#pragma unroll
            for (int mt = 0; mt < 4; ++mt)
#pragma unroll
                for (int r = 0; r < 4; ++r) {
                    float v = acc1[mt][nt][r] + bias1[nt];
                    v = v > 0.f ? v : 0.f;
                    hs[(mt * 16 + lq * 4 + r) * LDH + col] = f2bf(v);
                }
        }
        __syncthreads();

        // ---- GEMM2: out[64][128] = Hmid[64][256] @ W2c^T + b2s ----
        f32x4 acc2[4][2] = {};
        for (int ks = 0; ks < 8; ++ks) {
            const int kofs = ks * 32 + lq * 8;
            bf16x8 a[4], b[2];
#pragma unroll
            for (int mt = 0; mt < 4; ++mt)
                a[mt] = *(const bf16x8*)&hs[(mt * 16 + l16) * LDH + kofs];
#pragma unroll
            for (int nt = 0; nt < 2; ++nt)
                b[nt] = *(const bf16x8*)&W2c[(ncb2 + nt * 16 + l16) * 256 + kofs];
#pragma unroll
            for (int mt = 0; mt < 4; ++mt)
#pragma unroll
                for (int nt = 0; nt < 2; ++nt)
                    acc2[mt][nt] = __builtin_amdgcn_mfma_f32_16x16x32_bf16(
                        a[mt], b[nt], acc2[mt][nt], 0, 0, 0);
        }
        // epilogue: bias + nontemporal f32 store
        float* outp = out + (size_t)tile * (BM * HD);
#pragma unroll
        for (int nt = 0; nt < 2; ++nt) {
            const int col = ncb2 + nt * 16 + l16;
#pragma unroll
            for (int mt = 0; mt < 4; ++mt)
#pragma unroll
                for (int r = 0; r < 4; ++r)
                    __builtin_nontemporal_store(acc2[mt][nt][r] + bias2[nt],
                        &outp[(size_t)(mt * 16 + lq * 4 + r) * HD + col]);
        }

        tile = ntile;
    }
}

extern "C" void kernel_launch(void* const* d_in, const int* in_sizes, int n_in,
                              void* d_out, int out_size, void* d_ws, size_t ws_size,
                              hipStream_t stream) {
    const float* x      = (const float*)d_in[0];
    const float* x_real = (const float*)d_in[1];
    // d_in[2] = user_embedding (unused by reference)
    const float* uW1 = (const float*)d_in[3];
    const float* ub1 = (const float*)d_in[4];
    const float* uW2 = (const float*)d_in[5];
    const float* ub2 = (const float*)d_in[6];
    const float* eW1 = (const float*)d_in[7];
    const float* eb1 = (const float*)d_in[8];
    const float* eW2 = (const float*)d_in[9];
    const float* eb2 = (const float*)d_in[10];
    const float* sW1 = (const float*)d_in[11];
    const float* sb1 = (const float*)d_in[12];
    const float* sW2 = (const float*)d_in[13];
    const float* sb2 = (const float*)d_in[14];
    float* out = (float*)d_out;

    char* ws = (char*)d_ws;
    unsigned short* W1c = (unsigned short*)(ws + 64);
    unsigned short* W2c = (unsigned short*)(ws + 64 + 65536);
    float* b1c = (float*)(ws + 64 + 131072);
    float* b2s = (float*)(ws + 64 + 131072 + 1024);

    prep_route<<<128, 256, 0, stream>>>(x_real, sW1, sb1, sW2, sb2,
                                        uW1, ub1, uW2, ub2, eW1, eb1, eW2, eb2,
                                        out + (size_t)BATCH * LSEQ * HD,
                                        W1c, W2c, b1c, b2s);
    moe_main<<<GRID, 256, 0, stream>>>(x, W1c, W2c, b1c, b2s, out);
}

// Round 3
// 244.430 us; speedup vs baseline: 1.0132x; 1.0132x over previous
//
#include <hip/hip_runtime.h>

#define HD 128
#define LSEQ 200
#define BATCH 2048
#define NE 8
#define SWH 64

#define BM 32        // tokens per block
#define LDX 136      // padded bf16 row stride for x tile
#define LDH 264      // padded bf16 row stride for hidden tile

typedef float f32x4 __attribute__((ext_vector_type(4)));
typedef __bf16 bf16x8 __attribute__((ext_vector_type(8)));

static __device__ __forceinline__ unsigned short f2bf(float f) {
    union { float f; unsigned u; } v; v.f = f;
    unsigned u = v.u;
    u += 0x7fffu + ((u >> 16) & 1u);   // round-to-nearest-even
    return (unsigned short)(u >> 16);
}

// ---------------- fused routing + weight prep ----------------
// W1c [256][128]: rows 0-127 = uW1, rows 128-255 = eW1[route]
// W2c [128][256]: cols 0-127 = uW2, cols 128-255 = eW2[route]
__global__ void prep_route(const float* __restrict__ x_real,
                           const float* __restrict__ sW1, const float* __restrict__ sb1,
                           const float* __restrict__ sW2, const float* __restrict__ sb2,
                           const float* __restrict__ uW1, const float* __restrict__ ub1,
                           const float* __restrict__ uW2, const float* __restrict__ ub2,
                           const float* __restrict__ eW1, const float* __restrict__ eb1,
                           const float* __restrict__ eW2, const float* __restrict__ eb2,
                           float* __restrict__ out_tail,
                           unsigned short* __restrict__ W1c, unsigned short* __restrict__ W2c,
                           float* __restrict__ b1c, float* __restrict__ b2s) {
    __shared__ float part[256];
    __shared__ float xm[HD];
    __shared__ float hsw[SWH];
    __shared__ float logits[NE];
    __shared__ int route_s;
    const int t = threadIdx.x;   // 256 threads

    { // mean over sequence, two half-sums per column
        int col = t & 127, half = t >> 7;
        float s = 0.f;
        for (int l = half * 100; l < half * 100 + 100; ++l) s += x_real[l * HD + col];
        part[t] = s;
    }
    __syncthreads();
    if (t < HD) xm[t] = (part[t] + part[t + 128]) * (1.0f / LSEQ);
    __syncthreads();
    if (t < SWH) {
        float s = sb1[t];
        for (int k = 0; k < HD; ++k) s += xm[k] * sW1[t * HD + k];
        hsw[t] = s > 0.f ? s : 0.f;
    }
    __syncthreads();
    if (t < NE) {
        float s = sb2[t];
        for (int k = 0; k < SWH; ++k) s += hsw[k] * sW2[t * SWH + k];
        logits[t] = s;
    }
    __syncthreads();
    if (t == 0) {
        float mx = logits[0]; int am = 0;
        for (int e = 1; e < NE; ++e) if (logits[e] > mx) { mx = logits[e]; am = e; }
        float den = 0.f;
        for (int e = 0; e < NE; ++e) den += __expf(logits[e] - mx);
        route_s = am;
        if (blockIdx.x == 0) {
            out_tail[0] = (float)am;      // route
            out_tail[1] = 1.0f / den;     // out_prob_max = exp(0)/den
        }
    }
    __syncthreads();
    const int r = route_s;

    const int i = blockIdx.x * 256 + t;   // 0 .. 32767
    if (i < 2 * HD * HD) {
        int o = i >> 7, k = i & 127;
        float v1 = (o < HD) ? uW1[o * HD + k] : eW1[r * HD * HD + (o - HD) * HD + k];
        W1c[i] = f2bf(v1);
        int o2 = i >> 8, j = i & 255;
        float v2 = (j < HD) ? uW2[o2 * HD + j] : eW2[r * HD * HD + o2 * HD + (j - HD)];
        W2c[i] = f2bf(v2);
    }
    if (i < 2 * HD) b1c[i] = (i < HD) ? ub1[i] : eb1[r * HD + (i - HD)];
    if (i < HD)     b2s[i] = ub2[i] + eb2[r * HD + i];
}

// ---------------- main: fused 2-stage GEMM, BM=32, 6 blocks/CU ----------------
__global__ __launch_bounds__(256, 6)
void moe_main(const float* __restrict__ x,
              const unsigned short* __restrict__ W1c, const unsigned short* __restrict__ W2c,
              const float* __restrict__ b1c, const float* __restrict__ b2s,
              float* __restrict__ out) {
    __shared__ __align__(16) unsigned short xs[BM * LDX];  //  8704 B
    __shared__ __align__(16) unsigned short hs[BM * LDH];  // 16896 B

    const int t = threadIdx.x;
    const int lane = t & 63;
    const int w = t >> 6;          // wave 0..3
    const int l16 = lane & 15;
    const int lq = lane >> 4;      // quadrant 0..3
    const int ncb = w * 64;        // GEMM1: this wave's 64 hidden columns
    const int ncb2 = w * 32;       // GEMM2: this wave's 32 output columns
    const size_t base = (size_t)blockIdx.x * (BM * HD);

    // ---- stage x tile (f32 -> bf16) into LDS ----
    const float4* x4 = (const float4*)(x + base);
#pragma unroll
    for (int i = 0; i < 4; ++i) {
        int idx = t + i * 256;       // 0..1023 float4 units
        int row = idx >> 5;          // 32 float4 per row
        int c4 = idx & 31;
        float4 v = x4[idx];
        ushort4 b;
        b.x = f2bf(v.x); b.y = f2bf(v.y); b.z = f2bf(v.z); b.w = f2bf(v.w);
        *(ushort4*)&xs[row * LDX + c4 * 4] = b;
    }
    __syncthreads();

    // ---- GEMM1: Hmid[32][256] = relu(X[32][128] @ W1c^T + b1c) ----
    f32x4 acc1[2][4] = {};
    for (int ks = 0; ks < 4; ++ks) {
        const int kofs = ks * 32 + lq * 8;
        bf16x8 a[2], b[4];
#pragma unroll
        for (int mt = 0; mt < 2; ++mt)
            a[mt] = *(const bf16x8*)&xs[(mt * 16 + l16) * LDX + kofs];
#pragma unroll
        for (int nt = 0; nt < 4; ++nt)
            b[nt] = *(const bf16x8*)&W1c[(ncb + nt * 16 + l16) * HD + kofs];
#pragma unroll
        for (int mt = 0; mt < 2; ++mt)
#pragma unroll
            for (int nt = 0; nt < 4; ++nt)
                acc1[mt][nt] = __builtin_amdgcn_mfma_f32_16x16x32_bf16(
                    a[mt], b[nt], acc1[mt][nt], 0, 0, 0);
    }
    // bias + relu + store hidden to LDS (bf16)
#pragma unroll
    for (int nt = 0; nt < 4; ++nt) {
        const int col = ncb + nt * 16 + l16;
        const float bias = b1c[col];
#pragma unroll
        for (int mt = 0; mt < 2; ++mt)
#pragma unroll
            for (int r = 0; r < 4; ++r) {
                float v = acc1[mt][nt][r] + bias;
                v = v > 0.f ? v : 0.f;
                hs[(mt * 16 + lq * 4 + r) * LDH + col] = f2bf(v);
            }
    }
    __syncthreads();

    // ---- GEMM2: out[32][128] = Hmid[32][256] @ W2c^T + b2s ----
    f32x4 acc2[2][2] = {};
    for (int ks = 0; ks < 8; ++ks) {
        const int kofs = ks * 32 + lq * 8;
        bf16x8 a[2], b[2];
#pragma unroll
        for (int mt = 0; mt < 2; ++mt)
            a[mt] = *(const bf16x8*)&hs[(mt * 16 + l16) * LDH + kofs];
#pragma unroll
        for (int nt = 0; nt < 2; ++nt)
            b[nt] = *(const bf16x8*)&W2c[(ncb2 + nt * 16 + l16) * 256 + kofs];
#pragma unroll
        for (int mt = 0; mt < 2; ++mt)
#pragma unroll
            for (int nt = 0; nt < 2; ++nt)
                acc2[mt][nt] = __builtin_amdgcn_mfma_f32_16x16x32_bf16(
                    a[mt], b[nt], acc2[mt][nt], 0, 0, 0);
    }
    // epilogue: bias + plain f32 stores (L2 coalesces these fine — R1 WRITE was ideal)
    float* outp = out + base;
#pragma unroll
    for (int nt = 0; nt < 2; ++nt) {
        const int col = ncb2 + nt * 16 + l16;
        const float bias = b2s[col];
#pragma unroll
        for (int mt = 0; mt < 2; ++mt)
#pragma unroll
            for (int r = 0; r < 4; ++r)
                outp[(size_t)(mt * 16 + lq * 4 + r) * HD + col] = acc2[mt][nt][r] + bias;
    }
}

extern "C" void kernel_launch(void* const* d_in, const int* in_sizes, int n_in,
                              void* d_out, int out_size, void* d_ws, size_t ws_size,
                              hipStream_t stream) {
    const float* x      = (const float*)d_in[0];
    const float* x_real = (const float*)d_in[1];
    // d_in[2] = user_embedding (unused by reference)
    const float* uW1 = (const float*)d_in[3];
    const float* ub1 = (const float*)d_in[4];
    const float* uW2 = (const float*)d_in[5];
    const float* ub2 = (const float*)d_in[6];
    const float* eW1 = (const float*)d_in[7];
    const float* eb1 = (const float*)d_in[8];
    const float* eW2 = (const float*)d_in[9];
    const float* eb2 = (const float*)d_in[10];
    const float* sW1 = (const float*)d_in[11];
    const float* sb1 = (const float*)d_in[12];
    const float* sW2 = (const float*)d_in[13];
    const float* sb2 = (const float*)d_in[14];
    float* out = (float*)d_out;

    char* ws = (char*)d_ws;
    unsigned short* W1c = (unsigned short*)(ws + 64);
    unsigned short* W2c = (unsigned short*)(ws + 64 + 65536);
    float* b1c = (float*)(ws + 64 + 131072);
    float* b2s = (float*)(ws + 64 + 131072 + 1024);

    prep_route<<<128, 256, 0, stream>>>(x_real, sW1, sb1, sW2, sb2,
                                        uW1, ub1, uW2, ub2, eW1, eb1, eW2, eb2,
                                        out + (size_t)BATCH * LSEQ * HD,
                                        W1c, W2c, b1c, b2s);
    moe_main<<<(BATCH * LSEQ) / BM, 256, 0, stream>>>(x, W1c, W2c, b1c, b2s, out);
}

// Round 4
// 101.292 us; speedup vs baseline: 2.4450x; 2.4131x over previous
//
#include <hip/hip_runtime.h>

#define HD 128
#define LSEQ 200
#define BATCH 2048
#define NE 8
#define SWH 64

#define BM 32        // tokens per tile
#define LDX 136      // padded bf16 row stride for x tile
#define LDH 264      // padded bf16 row stride for hidden tile
#define NTILES ((BATCH * LSEQ) / BM)   // 12800
#define GRID 512     // persistent: 2 blocks/CU

typedef float f32x4 __attribute__((ext_vector_type(4)));
typedef __bf16 bf16x8 __attribute__((ext_vector_type(8)));

static __device__ __forceinline__ unsigned short f2bf(float f) {
    union { float f; unsigned u; } v; v.f = f;
    unsigned u = v.u;
    u += 0x7fffu + ((u >> 16) & 1u);   // round-to-nearest-even
    return (unsigned short)(u >> 16);
}

// ---------------- fused routing + weight prep ----------------
// W1c [256][128]: rows 0-127 = uW1, rows 128-255 = eW1[route]
// W2c [128][256]: cols 0-127 = uW2, cols 128-255 = eW2[route]
__global__ void prep_route(const float* __restrict__ x_real,
                           const float* __restrict__ sW1, const float* __restrict__ sb1,
                           const float* __restrict__ sW2, const float* __restrict__ sb2,
                           const float* __restrict__ uW1, const float* __restrict__ ub1,
                           const float* __restrict__ uW2, const float* __restrict__ ub2,
                           const float* __restrict__ eW1, const float* __restrict__ eb1,
                           const float* __restrict__ eW2, const float* __restrict__ eb2,
                           float* __restrict__ out_tail,
                           unsigned short* __restrict__ W1c, unsigned short* __restrict__ W2c,
                           float* __restrict__ b1c, float* __restrict__ b2s) {
    __shared__ float part[256];
    __shared__ float xm[HD];
    __shared__ float hsw[SWH];
    __shared__ float logits[NE];
    __shared__ int route_s;
    const int t = threadIdx.x;   // 256 threads

    { // mean over sequence, two half-sums per column
        int col = t & 127, half = t >> 7;
        float s = 0.f;
        for (int l = half * 100; l < half * 100 + 100; ++l) s += x_real[l * HD + col];
        part[t] = s;
    }
    __syncthreads();
    if (t < HD) xm[t] = (part[t] + part[t + 128]) * (1.0f / LSEQ);
    __syncthreads();
    if (t < SWH) {
        float s = sb1[t];
        for (int k = 0; k < HD; ++k) s += xm[k] * sW1[t * HD + k];
        hsw[t] = s > 0.f ? s : 0.f;
    }
    __syncthreads();
    if (t < NE) {
        float s = sb2[t];
        for (int k = 0; k < SWH; ++k) s += hsw[k] * sW2[t * SWH + k];
        logits[t] = s;
    }
    __syncthreads();
    if (t == 0) {
        float mx = logits[0]; int am = 0;
        for (int e = 1; e < NE; ++e) if (logits[e] > mx) { mx = logits[e]; am = e; }
        float den = 0.f;
        for (int e = 0; e < NE; ++e) den += __expf(logits[e] - mx);
        route_s = am;
        if (blockIdx.x == 0) {
            out_tail[0] = (float)am;      // route
            out_tail[1] = 1.0f / den;     // out_prob_max = exp(0)/den
        }
    }
    __syncthreads();
    const int r = route_s;

    const int i = blockIdx.x * 256 + t;   // 0 .. 32767
    if (i < 2 * HD * HD) {
        int o = i >> 7, k = i & 127;
        float v1 = (o < HD) ? uW1[o * HD + k] : eW1[r * HD * HD + (o - HD) * HD + k];
        W1c[i] = f2bf(v1);
        int o2 = i >> 8, j = i & 255;
        float v2 = (j < HD) ? uW2[o2 * HD + j] : eW2[r * HD * HD + o2 * HD + (j - HD)];
        W2c[i] = f2bf(v2);
    }
    if (i < 2 * HD) b1c[i] = (i < HD) ? ub1[i] : eb1[r * HD + (i - HD)];
    if (i < HD)     b2s[i] = ub2[i] + eb2[r * HD + i];
}

// ---------------- main: persistent blocks, weights resident in VGPRs ----------------
__global__ __launch_bounds__(256, 2)
void moe_main(const float* __restrict__ x,
              const unsigned short* __restrict__ W1c, const unsigned short* __restrict__ W2c,
              const float* __restrict__ b1c, const float* __restrict__ b2s,
              float* __restrict__ out) {
    __shared__ __align__(16) unsigned short xs[BM * LDX];  //  8704 B
    __shared__ __align__(16) unsigned short hs[BM * LDH];  // 16896 B

    const int t = threadIdx.x;
    const int lane = t & 63;
    const int w = t >> 6;          // wave 0..3
    const int l16 = lane & 15;
    const int lq = lane >> 4;      // quadrant 0..3
    const int ncb = w * 64;        // GEMM1: this wave's 64 hidden columns
    const int ncb2 = w * 32;       // GEMM2: this wave's 32 output columns

    // ---- load this wave's weight fragments into registers (ONCE per block) ----
    bf16x8 w1[4][4];   // [ks][nt] for GEMM1
    bf16x8 w2[8][2];   // [ks][nt] for GEMM2
#pragma unroll
    for (int ks = 0; ks < 4; ++ks)
#pragma unroll
        for (int nt = 0; nt < 4; ++nt)
            w1[ks][nt] = *(const bf16x8*)&W1c[(ncb + nt * 16 + l16) * HD + ks * 32 + lq * 8];
#pragma unroll
    for (int ks = 0; ks < 8; ++ks)
#pragma unroll
        for (int nt = 0; nt < 2; ++nt)
            w2[ks][nt] = *(const bf16x8*)&W2c[(ncb2 + nt * 16 + l16) * 256 + ks * 32 + lq * 8];

    float bias1[4], bias2[2];
#pragma unroll
    for (int nt = 0; nt < 4; ++nt) bias1[nt] = b1c[ncb + nt * 16 + l16];
#pragma unroll
    for (int nt = 0; nt < 2; ++nt) bias2[nt] = b2s[ncb2 + nt * 16 + l16];

    int tile = blockIdx.x;
    float4 pv[4];
    { // prefetch first tile (4 float4/thread = 32x128 f32)
        const float4* x4 = (const float4*)(x + (size_t)tile * (BM * HD));
#pragma unroll
        for (int i = 0; i < 4; ++i) pv[i] = x4[t + i * 256];
    }

    while (tile < NTILES) {
        const int ntile = tile + GRID;

        // ---- stage prefetched x tile (f32 -> bf16) into LDS ----
#pragma unroll
        for (int i = 0; i < 4; ++i) {
            int idx = t + i * 256;       // 0..1023 float4 units
            int row = idx >> 5;          // 32 float4 per row
            int c4 = idx & 31;
            ushort4 b;
            b.x = f2bf(pv[i].x); b.y = f2bf(pv[i].y);
            b.z = f2bf(pv[i].z); b.w = f2bf(pv[i].w);
            *(ushort4*)&xs[row * LDX + c4 * 4] = b;
        }

        // ---- issue next tile's global loads (consumed next iteration; hides HBM/L3 latency) ----
        if (ntile < NTILES) {
            const float4* x4 = (const float4*)(x + (size_t)ntile * (BM * HD));
#pragma unroll
            for (int i = 0; i < 4; ++i) pv[i] = x4[t + i * 256];
        }
        __syncthreads();

        // ---- GEMM1: Hmid[32][256] = relu(X[32][128] @ W1c^T + b1c) — pure LDS+MFMA ----
        f32x4 acc1[2][4] = {};
#pragma unroll
        for (int ks = 0; ks < 4; ++ks) {
            const int kofs = ks * 32 + lq * 8;
            bf16x8 a[2];
#pragma unroll
            for (int mt = 0; mt < 2; ++mt)
                a[mt] = *(const bf16x8*)&xs[(mt * 16 + l16) * LDX + kofs];
#pragma unroll
            for (int mt = 0; mt < 2; ++mt)
#pragma unroll
                for (int nt = 0; nt < 4; ++nt)
                    acc1[mt][nt] = __builtin_amdgcn_mfma_f32_16x16x32_bf16(
                        a[mt], w1[ks][nt], acc1[mt][nt], 0, 0, 0);
        }
        // bias + relu + store hidden to LDS (bf16)
#pragma unroll
        for (int nt = 0; nt < 4; ++nt) {
            const int col = ncb + nt * 16 + l16;
#pragma unroll
            for (int mt = 0; mt < 2; ++mt)
#pragma unroll
                for (int r = 0; r < 4; ++r) {
                    float v = acc1[mt][nt][r] + bias1[nt];
                    v = v > 0.f ? v : 0.f;
                    hs[(mt * 16 + lq * 4 + r) * LDH + col] = f2bf(v);
                }
        }
        __syncthreads();

        // ---- GEMM2: out[32][128] = Hmid[32][256] @ W2c^T + b2s — pure LDS+MFMA ----
        f32x4 acc2[2][2] = {};
#pragma unroll
        for (int ks = 0; ks < 8; ++ks) {
            const int kofs = ks * 32 + lq * 8;
            bf16x8 a[2];
#pragma unroll
            for (int mt = 0; mt < 2; ++mt)
                a[mt] = *(const bf16x8*)&hs[(mt * 16 + l16) * LDH + kofs];
#pragma unroll
            for (int mt = 0; mt < 2; ++mt)
#pragma unroll
                for (int nt = 0; nt < 2; ++nt)
                    acc2[mt][nt] = __builtin_amdgcn_mfma_f32_16x16x32_bf16(
                        a[mt], w2[ks][nt], acc2[mt][nt], 0, 0, 0);
        }
        // epilogue: bias + plain f32 stores (L2 coalesces; NT was 2x worse)
        float* outp = out + (size_t)tile * (BM * HD);
#pragma unroll
        for (int nt = 0; nt < 2; ++nt) {
            const int col = ncb2 + nt * 16 + l16;
#pragma unroll
            for (int mt = 0; mt < 2; ++mt)
#pragma unroll
                for (int r = 0; r < 4; ++r)
                    outp[(size_t)(mt * 16 + lq * 4 + r) * HD + col] = acc2[mt][nt][r] + bias2[nt];
        }

        tile = ntile;
    }
}

extern "C" void kernel_launch(void* const* d_in, const int* in_sizes, int n_in,
                              void* d_out, int out_size, void* d_ws, size_t ws_size,
                              hipStream_t stream) {
    const float* x      = (const float*)d_in[0];
    const float* x_real = (const float*)d_in[1];
    // d_in[2] = user_embedding (unused by reference)
    const float* uW1 = (const float*)d_in[3];
    const float* ub1 = (const float*)d_in[4];
    const float* uW2 = (const float*)d_in[5];
    const float* ub2 = (const float*)d_in[6];
    const float* eW1 = (const float*)d_in[7];
    const float* eb1 = (const float*)d_in[8];
    const float* eW2 = (const float*)d_in[9];
    const float* eb2 = (const float*)d_in[10];
    const float* sW1 = (const float*)d_in[11];
    const float* sb1 = (const float*)d_in[12];
    const float* sW2 = (const float*)d_in[13];
    const float* sb2 = (const float*)d_in[14];
    float* out = (float*)d_out;

    char* ws = (char*)d_ws;
    unsigned short* W1c = (unsigned short*)(ws + 64);
    unsigned short* W2c = (unsigned short*)(ws + 64 + 65536);
    float* b1c = (float*)(ws + 64 + 131072);
    float* b2s = (float*)(ws + 64 + 131072 + 1024);

    prep_route<<<128, 256, 0, stream>>>(x_real, sW1, sb1, sW2, sb2,
                                        uW1, ub1, uW2, ub2, eW1, eb1, eW2, eb2,
                                        out + (size_t)BATCH * LSEQ * HD,
                                        W1c, W2c, b1c, b2s);
    moe_main<<<GRID, 256, 0, stream>>>(x, W1c, W2c, b1c, b2s, out);
}

// Round 5
// 99.722 us; speedup vs baseline: 2.4835x; 1.0157x over previous
//
#include <hip/hip_runtime.h>

#define HD 128
#define LSEQ 200
#define BATCH 2048
#define NE 8
#define SWH 64

#define BM 32        // tokens per tile
#define LDX 136      // padded bf16 row stride for x tile
#define LDH 264      // padded bf16 row stride for hidden tile
#define NTILES ((BATCH * LSEQ) / BM)   // 12800
#define GRID 512     // persistent: 2 blocks/CU

typedef float f32x4 __attribute__((ext_vector_type(4)));
typedef __bf16 bf16x4 __attribute__((ext_vector_type(4)));
typedef __bf16 bf16x8 __attribute__((ext_vector_type(8)));

static __device__ __forceinline__ unsigned short f2bf(float f) {
    union { float f; unsigned u; } v; v.f = f;
    unsigned u = v.u;
    u += 0x7fffu + ((u >> 16) & 1u);   // round-to-nearest-even
    return (unsigned short)(u >> 16);
}

// ---------------- fused routing + weight prep ----------------
// W1c [256][128]: rows 0-127 = uW1, rows 128-255 = eW1[route]
// W2c [128][256]: cols 0-127 = uW2, cols 128-255 = eW2[route]
__global__ void prep_route(const float* __restrict__ x_real,
                           const float* __restrict__ sW1, const float* __restrict__ sb1,
                           const float* __restrict__ sW2, const float* __restrict__ sb2,
                           const float* __restrict__ uW1, const float* __restrict__ ub1,
                           const float* __restrict__ uW2, const float* __restrict__ ub2,
                           const float* __restrict__ eW1, const float* __restrict__ eb1,
                           const float* __restrict__ eW2, const float* __restrict__ eb2,
                           float* __restrict__ out_tail,
                           unsigned short* __restrict__ W1c, unsigned short* __restrict__ W2c,
                           float* __restrict__ b1c, float* __restrict__ b2s) {
    __shared__ float part[256];
    __shared__ float xm[HD];
    __shared__ float hsw[SWH];
    __shared__ float logits[NE];
    __shared__ int route_s;
    const int t = threadIdx.x;   // 256 threads

    { // mean over sequence, two half-sums per column
        int col = t & 127, half = t >> 7;
        float s = 0.f;
        for (int l = half * 100; l < half * 100 + 100; ++l) s += x_real[l * HD + col];
        part[t] = s;
    }
    __syncthreads();
    if (t < HD) xm[t] = (part[t] + part[t + 128]) * (1.0f / LSEQ);
    __syncthreads();
    if (t < SWH) {
        float s = sb1[t];
        for (int k = 0; k < HD; ++k) s += xm[k] * sW1[t * HD + k];
        hsw[t] = s > 0.f ? s : 0.f;
    }
    __syncthreads();
    if (t < NE) {
        float s = sb2[t];
        for (int k = 0; k < SWH; ++k) s += hsw[k] * sW2[t * SWH + k];
        logits[t] = s;
    }
    __syncthreads();
    if (t == 0) {
        float mx = logits[0]; int am = 0;
        for (int e = 1; e < NE; ++e) if (logits[e] > mx) { mx = logits[e]; am = e; }
        float den = 0.f;
        for (int e = 0; e < NE; ++e) den += __expf(logits[e] - mx);
        route_s = am;
        if (blockIdx.x == 0) {
            out_tail[0] = (float)am;      // route
            out_tail[1] = 1.0f / den;     // out_prob_max = exp(0)/den
        }
    }
    __syncthreads();
    const int r = route_s;

    const int i = blockIdx.x * 256 + t;   // 0 .. 32767
    if (i < 2 * HD * HD) {
        int o = i >> 7, k = i & 127;
        float v1 = (o < HD) ? uW1[o * HD + k] : eW1[r * HD * HD + (o - HD) * HD + k];
        W1c[i] = f2bf(v1);
        int o2 = i >> 8, j = i & 255;
        float v2 = (j < HD) ? uW2[o2 * HD + j] : eW2[r * HD * HD + o2 * HD + (j - HD)];
        W2c[i] = f2bf(v2);
    }
    if (i < 2 * HD) b1c[i] = (i < HD) ? ub1[i] : eb1[r * HD + (i - HD)];
    if (i < HD)     b2s[i] = ub2[i] + eb2[r * HD + i];
}

// ---------------- main: persistent, weights in regs, SWAPPED GEMMs ----------------
// GEMM1 computes Hmid^T = W1c · X^T  (lane owns 4 consecutive hidden cols of one token)
// GEMM2 computes out^T  = W2c · Hmid^T (lane owns 4 consecutive out cols of one token)
// -> packed b64 LDS writes and dwordx4 global stores; all fragment LOADS unchanged.
__global__ __launch_bounds__(256, 2)
void moe_main(const float* __restrict__ x,
              const unsigned short* __restrict__ W1c, const unsigned short* __restrict__ W2c,
              const float* __restrict__ b1c, const float* __restrict__ b2s,
              float* __restrict__ out) {
    __shared__ __align__(16) unsigned short xs[BM * LDX];  //  8704 B
    __shared__ __align__(16) unsigned short hs[BM * LDH];  // 16896 B

    const int t = threadIdx.x;
    const int lane = t & 63;
    const int w = t >> 6;          // wave 0..3
    const int l16 = lane & 15;
    const int lq = lane >> 4;      // quadrant 0..3
    const int ncb = w * 64;        // GEMM1: this wave's 64 hidden cols
    const int ncb2 = w * 32;       // GEMM2: this wave's 32 output cols

    // ---- load this wave's weight fragments into registers (ONCE) ----
    bf16x8 w1[4][4];   // [ks][ht]  A-operand rows = hidden cols
    bf16x8 w2[8][2];   // [ks][ct]  A-operand rows = output cols
#pragma unroll
    for (int ks = 0; ks < 4; ++ks)
#pragma unroll
        for (int ht = 0; ht < 4; ++ht)
            w1[ks][ht] = *(const bf16x8*)&W1c[(ncb + ht * 16 + l16) * HD + ks * 32 + lq * 8];
#pragma unroll
    for (int ks = 0; ks < 8; ++ks)
#pragma unroll
        for (int ct = 0; ct < 2; ++ct)
            w2[ks][ct] = *(const bf16x8*)&W2c[(ncb2 + ct * 16 + l16) * 256 + ks * 32 + lq * 8];

    // bias vectors across the 4 C-layout rows (r = reg index)
    f32x4 bias1v[4], bias2v[2];
#pragma unroll
    for (int ht = 0; ht < 4; ++ht) bias1v[ht] = *(const f32x4*)&b1c[ncb + ht * 16 + lq * 4];
#pragma unroll
    for (int ct = 0; ct < 2; ++ct) bias2v[ct] = *(const f32x4*)&b2s[ncb2 + ct * 16 + lq * 4];

    int tile = blockIdx.x;
    float4 pv[4];
    { // prefetch first tile (4 float4/thread = 32x128 f32)
        const float4* x4 = (const float4*)(x + (size_t)tile * (BM * HD));
#pragma unroll
        for (int i = 0; i < 4; ++i) pv[i] = x4[t + i * 256];
    }

    while (tile < NTILES) {
        const int ntile = tile + GRID;

        // ---- stage prefetched x tile (f32 -> bf16, packed b64 writes) ----
#pragma unroll
        for (int i = 0; i < 4; ++i) {
            int idx = t + i * 256;       // 0..1023 float4 units
            int row = idx >> 5;          // 32 float4 per row
            int c4 = idx & 31;
            bf16x4 b;
            b[0] = (__bf16)pv[i].x; b[1] = (__bf16)pv[i].y;
            b[2] = (__bf16)pv[i].z; b[3] = (__bf16)pv[i].w;
            *(bf16x4*)&xs[row * LDX + c4 * 4] = b;
        }

        // ---- issue next tile's global loads (consumed next iteration) ----
        if (ntile < NTILES) {
            const float4* x4 = (const float4*)(x + (size_t)ntile * (BM * HD));
#pragma unroll
            for (int i = 0; i < 4; ++i) pv[i] = x4[t + i * 256];
        }
        __syncthreads();

        // ---- GEMM1 (swapped): Hmid^T = W1c · X^T ----
        f32x4 acc1[4][2] = {};
#pragma unroll
        for (int ks = 0; ks < 4; ++ks) {
            const int kofs = ks * 32 + lq * 8;
            bf16x8 xf[2];
#pragma unroll
            for (int tt = 0; tt < 2; ++tt)
                xf[tt] = *(const bf16x8*)&xs[(tt * 16 + l16) * LDX + kofs];
#pragma unroll
            for (int ht = 0; ht < 4; ++ht)
#pragma unroll
                for (int tt = 0; tt < 2; ++tt)
                    acc1[ht][tt] = __builtin_amdgcn_mfma_f32_16x16x32_bf16(
                        w1[ks][ht], xf[tt], acc1[ht][tt], 0, 0, 0);
        }
        // bias + relu + packed b64 store of 4 consecutive hidden cols per token
#pragma unroll
        for (int ht = 0; ht < 4; ++ht)
#pragma unroll
            for (int tt = 0; tt < 2; ++tt) {
                bf16x4 hv;
#pragma unroll
                for (int r = 0; r < 4; ++r) {
                    float v = acc1[ht][tt][r] + bias1v[ht][r];
                    hv[r] = (__bf16)(v > 0.f ? v : 0.f);
                }
                *(bf16x4*)&hs[(tt * 16 + l16) * LDH + ncb + ht * 16 + lq * 4] = hv;
            }
        __syncthreads();

        // ---- GEMM2 (swapped): out^T = W2c · Hmid^T ----
        f32x4 acc2[2][2] = {};
#pragma unroll
        for (int ks = 0; ks < 8; ++ks) {
            const int kofs = ks * 32 + lq * 8;
            bf16x8 hf[2];
#pragma unroll
            for (int tt = 0; tt < 2; ++tt)
                hf[tt] = *(const bf16x8*)&hs[(tt * 16 + l16) * LDH + kofs];
#pragma unroll
            for (int ct = 0; ct < 2; ++ct)
#pragma unroll
                for (int tt = 0; tt < 2; ++tt)
                    acc2[ct][tt] = __builtin_amdgcn_mfma_f32_16x16x32_bf16(
                        w2[ks][ct], hf[tt], acc2[ct][tt], 0, 0, 0);
        }
        // epilogue: bias + float4 stores (4 consecutive out cols per token)
        float* outp = out + (size_t)tile * (BM * HD);
#pragma unroll
        for (int ct = 0; ct < 2; ++ct)
#pragma unroll
            for (int tt = 0; tt < 2; ++tt) {
                f32x4 o;
#pragma unroll
                for (int r = 0; r < 4; ++r) o[r] = acc2[ct][tt][r] + bias2v[ct][r];
                *(f32x4*)&outp[(size_t)(tt * 16 + l16) * HD + ncb2 + ct * 16 + lq * 4] = o;
            }

        tile = ntile;
    }
}

extern "C" void kernel_launch(void* const* d_in, const int* in_sizes, int n_in,
                              void* d_out, int out_size, void* d_ws, size_t ws_size,
                              hipStream_t stream) {
    const float* x      = (const float*)d_in[0];
    const float* x_real = (const float*)d_in[1];
    // d_in[2] = user_embedding (unused by reference)
    const float* uW1 = (const float*)d_in[3];
    const float* ub1 = (const float*)d_in[4];
    const float* uW2 = (const float*)d_in[5];
    const float* ub2 = (const float*)d_in[6];
    const float* eW1 = (const float*)d_in[7];
    const float* eb1 = (const float*)d_in[8];
    const float* eW2 = (const float*)d_in[9];
    const float* eb2 = (const float*)d_in[10];
    const float* sW1 = (const float*)d_in[11];
    const float* sb1 = (const float*)d_in[12];
    const float* sW2 = (const float*)d_in[13];
    const float* sb2 = (const float*)d_in[14];
    float* out = (float*)d_out;

    char* ws = (char*)d_ws;
    unsigned short* W1c = (unsigned short*)(ws + 64);
    unsigned short* W2c = (unsigned short*)(ws + 64 + 65536);
    float* b1c = (float*)(ws + 64 + 131072);
    float* b2s = (float*)(ws + 64 + 131072 + 1024);

    prep_route<<<128, 256, 0, stream>>>(x_real, sW1, sb1, sW2, sb2,
                                        uW1, ub1, uW2, ub2, eW1, eb1, eW2, eb2,
                                        out + (size_t)BATCH * LSEQ * HD,
                                        W1c, W2c, b1c, b2s);
    moe_main<<<GRID, 256, 0, stream>>>(x, W1c, W2c, b1c, b2s, out);
}

// Round 6
// 98.649 us; speedup vs baseline: 2.5105x; 1.0109x over previous
//
#include <hip/hip_runtime.h>

#define HD 128
#define LSEQ 200
#define BATCH 2048
#define NE 8
#define SWH 64

#define BM 32        // tokens per tile
#define LDX 136      // padded bf16 row stride for x tile
#define LDH 264      // padded bf16 row stride for hidden tile
#define NTILES ((BATCH * LSEQ) / BM)   // 12800
#define GRID 512     // persistent: 2 blocks/CU

typedef float f32x4 __attribute__((ext_vector_type(4)));
typedef __bf16 bf16x4 __attribute__((ext_vector_type(4)));
typedef __bf16 bf16x8 __attribute__((ext_vector_type(8)));

// Raw barrier: per-wave LDS drain + s_barrier, WITHOUT the compiler's
// vmcnt(0) drain (which was synchronously eating global-load latency
// every iteration). Hazards: only LDS producer->consumer crosses these
// barriers; global loads/stores have no cross-wave hazard here.
#define BAR() do {                                          \
    asm volatile("s_waitcnt lgkmcnt(0)" ::: "memory");      \
    __builtin_amdgcn_sched_barrier(0);                      \
    __builtin_amdgcn_s_barrier();                           \
    __builtin_amdgcn_sched_barrier(0);                      \
} while (0)

static __device__ __forceinline__ unsigned short f2bf(float f) {
    union { float f; unsigned u; } v; v.f = f;
    unsigned u = v.u;
    u += 0x7fffu + ((u >> 16) & 1u);   // round-to-nearest-even
    return (unsigned short)(u >> 16);
}

// ---------------- fused routing + weight prep ----------------
// W1c [256][128]: rows 0-127 = uW1, rows 128-255 = eW1[route]
// W2c [128][256]: cols 0-127 = uW2, cols 128-255 = eW2[route]
__global__ void prep_route(const float* __restrict__ x_real,
                           const float* __restrict__ sW1, const float* __restrict__ sb1,
                           const float* __restrict__ sW2, const float* __restrict__ sb2,
                           const float* __restrict__ uW1, const float* __restrict__ ub1,
                           const float* __restrict__ uW2, const float* __restrict__ ub2,
                           const float* __restrict__ eW1, const float* __restrict__ eb1,
                           const float* __restrict__ eW2, const float* __restrict__ eb2,
                           float* __restrict__ out_tail,
                           unsigned short* __restrict__ W1c, unsigned short* __restrict__ W2c,
                           float* __restrict__ b1c, float* __restrict__ b2s) {
    __shared__ float part[256];
    __shared__ float xm[HD];
    __shared__ float hsw[SWH];
    __shared__ float logits[NE];
    __shared__ int route_s;
    const int t = threadIdx.x;   // 256 threads

    { // mean over sequence, two half-sums per column
        int col = t & 127, half = t >> 7;
        float s = 0.f;
        for (int l = half * 100; l < half * 100 + 100; ++l) s += x_real[l * HD + col];
        part[t] = s;
    }
    __syncthreads();
    if (t < HD) xm[t] = (part[t] + part[t + 128]) * (1.0f / LSEQ);
    __syncthreads();
    if (t < SWH) {
        float s = sb1[t];
        for (int k = 0; k < HD; ++k) s += xm[k] * sW1[t * HD + k];
        hsw[t] = s > 0.f ? s : 0.f;
    }
    __syncthreads();
    if (t < NE) {
        float s = sb2[t];
        for (int k = 0; k < SWH; ++k) s += hsw[k] * sW2[t * SWH + k];
        logits[t] = s;
    }
    __syncthreads();
    if (t == 0) {
        float mx = logits[0]; int am = 0;
        for (int e = 1; e < NE; ++e) if (logits[e] > mx) { mx = logits[e]; am = e; }
        float den = 0.f;
        for (int e = 0; e < NE; ++e) den += __expf(logits[e] - mx);
        route_s = am;
        if (blockIdx.x == 0) {
            out_tail[0] = (float)am;      // route
            out_tail[1] = 1.0f / den;     // out_prob_max = exp(0)/den
        }
    }
    __syncthreads();
    const int r = route_s;

    const int i = blockIdx.x * 256 + t;   // 0 .. 32767
    if (i < 2 * HD * HD) {
        int o = i >> 7, k = i & 127;
        float v1 = (o < HD) ? uW1[o * HD + k] : eW1[r * HD * HD + (o - HD) * HD + k];
        W1c[i] = f2bf(v1);
        int o2 = i >> 8, j = i & 255;
        float v2 = (j < HD) ? uW2[o2 * HD + j] : eW2[r * HD * HD + o2 * HD + (j - HD)];
        W2c[i] = f2bf(v2);
    }
    if (i < 2 * HD) b1c[i] = (i < HD) ? ub1[i] : eb1[r * HD + (i - HD)];
    if (i < HD)     b2s[i] = ub2[i] + eb2[r * HD + i];
}

// ---------------- main: persistent, weights in regs, swapped GEMMs, raw barriers ----------------
__global__ __launch_bounds__(256, 2)
void moe_main(const float* __restrict__ x,
              const unsigned short* __restrict__ W1c, const unsigned short* __restrict__ W2c,
              const float* __restrict__ b1c, const float* __restrict__ b2s,
              float* __restrict__ out) {
    __shared__ __align__(16) unsigned short xs[BM * LDX];  //  8704 B
    __shared__ __align__(16) unsigned short hs[BM * LDH];  // 16896 B

    const int t = threadIdx.x;
    const int lane = t & 63;
    const int w = t >> 6;          // wave 0..3
    const int l16 = lane & 15;
    const int lq = lane >> 4;      // quadrant 0..3
    const int ncb = w * 64;        // GEMM1: this wave's 64 hidden cols
    const int ncb2 = w * 32;       // GEMM2: this wave's 32 output cols

    // ---- load this wave's weight fragments into registers (ONCE) ----
    bf16x8 w1[4][4];   // [ks][ht]
    bf16x8 w2[8][2];   // [ks][ct]
#pragma unroll
    for (int ks = 0; ks < 4; ++ks)
#pragma unroll
        for (int ht = 0; ht < 4; ++ht)
            w1[ks][ht] = *(const bf16x8*)&W1c[(ncb + ht * 16 + l16) * HD + ks * 32 + lq * 8];
#pragma unroll
    for (int ks = 0; ks < 8; ++ks)
#pragma unroll
        for (int ct = 0; ct < 2; ++ct)
            w2[ks][ct] = *(const bf16x8*)&W2c[(ncb2 + ct * 16 + l16) * 256 + ks * 32 + lq * 8];

    f32x4 bias1v[4], bias2v[2];
#pragma unroll
    for (int ht = 0; ht < 4; ++ht) bias1v[ht] = *(const f32x4*)&b1c[ncb + ht * 16 + lq * 4];
#pragma unroll
    for (int ct = 0; ct < 2; ++ct) bias2v[ct] = *(const f32x4*)&b2s[ncb2 + ct * 16 + lq * 4];

    int tile = blockIdx.x;
    float4 pv[4];
    { // prefetch first tile
        const float4* x4 = (const float4*)(x + (size_t)tile * (BM * HD));
#pragma unroll
        for (int i = 0; i < 4; ++i) pv[i] = x4[t + i * 256];
    }

    while (tile < NTILES) {
        const int ntile = tile + GRID;

        // ---- stage prefetched x tile (f32 -> bf16, packed b64 writes) ----
#pragma unroll
        for (int i = 0; i < 4; ++i) {
            int idx = t + i * 256;       // 0..1023 float4 units
            int row = idx >> 5;          // 32 float4 per row
            int c4 = idx & 31;
            bf16x4 b;
            b[0] = (__bf16)pv[i].x; b[1] = (__bf16)pv[i].y;
            b[2] = (__bf16)pv[i].z; b[3] = (__bf16)pv[i].w;
            *(bf16x4*)&xs[row * LDX + c4 * 4] = b;
        }

        // ---- issue next tile's loads; they stay in flight ACROSS the raw barriers ----
        if (ntile < NTILES) {
            const float4* x4 = (const float4*)(x + (size_t)ntile * (BM * HD));
#pragma unroll
            for (int i = 0; i < 4; ++i) pv[i] = x4[t + i * 256];
        }
        BAR();   // xs ready (lgkm only — no vmcnt drain)

        // ---- GEMM1 (swapped): Hmid^T = W1c · X^T ----
        f32x4 acc1[4][2] = {};
#pragma unroll
        for (int ks = 0; ks < 4; ++ks) {
            const int kofs = ks * 32 + lq * 8;
            bf16x8 xf[2];
#pragma unroll
            for (int tt = 0; tt < 2; ++tt)
                xf[tt] = *(const bf16x8*)&xs[(tt * 16 + l16) * LDX + kofs];
#pragma unroll
            for (int ht = 0; ht < 4; ++ht)
#pragma unroll
                for (int tt = 0; tt < 2; ++tt)
                    acc1[ht][tt] = __builtin_amdgcn_mfma_f32_16x16x32_bf16(
                        w1[ks][ht], xf[tt], acc1[ht][tt], 0, 0, 0);
        }
        // bias + relu + packed b64 store of 4 consecutive hidden cols per token
#pragma unroll
        for (int ht = 0; ht < 4; ++ht)
#pragma unroll
            for (int tt = 0; tt < 2; ++tt) {
                bf16x4 hv;
#pragma unroll
                for (int r = 0; r < 4; ++r) {
                    float v = acc1[ht][tt][r] + bias1v[ht][r];
                    hv[r] = (__bf16)(v > 0.f ? v : 0.f);
                }
                *(bf16x4*)&hs[(tt * 16 + l16) * LDH + ncb + ht * 16 + lq * 4] = hv;
            }
        BAR();   // hs ready

        // ---- GEMM2 (swapped): out^T = W2c · Hmid^T ----
        f32x4 acc2[2][2] = {};
#pragma unroll
        for (int ks = 0; ks < 8; ++ks) {
            const int kofs = ks * 32 + lq * 8;
            bf16x8 hf[2];
#pragma unroll
            for (int tt = 0; tt < 2; ++tt)
                hf[tt] = *(const bf16x8*)&hs[(tt * 16 + l16) * LDH + kofs];
#pragma unroll
            for (int ct = 0; ct < 2; ++ct)
#pragma unroll
                for (int tt = 0; tt < 2; ++tt)
                    acc2[ct][tt] = __builtin_amdgcn_mfma_f32_16x16x32_bf16(
                        w2[ks][ct], hf[tt], acc2[ct][tt], 0, 0, 0);
        }
        // epilogue: bias + float4 stores
        float* outp = out + (size_t)tile * (BM * HD);
#pragma unroll
        for (int ct = 0; ct < 2; ++ct)
#pragma unroll
            for (int tt = 0; tt < 2; ++tt) {
                f32x4 o;
#pragma unroll
                for (int r = 0; r < 4; ++r) o[r] = acc2[ct][tt][r] + bias2v[ct][r];
                *(f32x4*)&outp[(size_t)(tt * 16 + l16) * HD + ncb2 + ct * 16 + lq * 4] = o;
            }

        tile = ntile;
    }
}

extern "C" void kernel_launch(void* const* d_in, const int* in_sizes, int n_in,
                              void* d_out, int out_size, void* d_ws, size_t ws_size,
                              hipStream_t stream) {
    const float* x      = (const float*)d_in[0];
    const float* x_real = (const float*)d_in[1];
    // d_in[2] = user_embedding (unused by reference)
    const float* uW1 = (const float*)d_in[3];
    const float* ub1 = (const float*)d_in[4];
    const float* uW2 = (const float*)d_in[5];
    const float* ub2 = (const float*)d_in[6];
    const float* eW1 = (const float*)d_in[7];
    const float* eb1 = (const float*)d_in[8];
    const float* eW2 = (const float*)d_in[9];
    const float* eb2 = (const float*)d_in[10];
    const float* sW1 = (const float*)d_in[11];
    const float* sb1 = (const float*)d_in[12];
    const float* sW2 = (const float*)d_in[13];
    const float* sb2 = (const float*)d_in[14];
    float* out = (float*)d_out;

    char* ws = (char*)d_ws;
    unsigned short* W1c = (unsigned short*)(ws + 64);
    unsigned short* W2c = (unsigned short*)(ws + 64 + 65536);
    float* b1c = (float*)(ws + 64 + 131072);
    float* b2s = (float*)(ws + 64 + 131072 + 1024);

    prep_route<<<128, 256, 0, stream>>>(x_real, sW1, sb1, sW2, sb2,
                                        uW1, ub1, uW2, ub2, eW1, eb1, eW2, eb2,
                                        out + (size_t)BATCH * LSEQ * HD,
                                        W1c, W2c, b1c, b2s);
    moe_main<<<GRID, 256, 0, stream>>>(x, W1c, W2c, b1c, b2s, out);
}